// Round 1
// 7350.253 us; speedup vs baseline: 1.3369x; 1.3369x over previous
//
#include <hip/hip_runtime.h>
#include <hip/hip_bf16.h>

// Seq2Seq: B=64 S=64 T=32 E=512 U=1024 VE=16000 VD=32000
// fp32 in/out; internal GEMMs bf16 MFMA.
// R1: fused LSTM-step kernel (zh-GEMM + gates [+ q-GEMM] in one launch,
//     h double-buffered), logits GEMM grid-swap for W reuse, vectorized attn.

typedef __hip_bfloat16 bf16;
typedef __bf16 bf16x8 __attribute__((ext_vector_type(8)));
typedef __bf16 bf16x4 __attribute__((ext_vector_type(4)));
typedef float f32x4 __attribute__((ext_vector_type(4)));

#define B_ 64
#define S_ 64
#define T_ 32
#define E_ 512
#define U_ 1024
#define VD_ 32000

__device__ __forceinline__ float sigf(float x) { return 1.0f / (1.0f + __expf(-x)); }

__device__ __forceinline__ bf16x8 frag_from_f32(const float* __restrict__ p) {
    float4 a = *(const float4*)p;
    float4 b = *(const float4*)(p + 4);
    bf16x8 r;
    r[0] = (__bf16)a.x; r[1] = (__bf16)a.y; r[2] = (__bf16)a.z; r[3] = (__bf16)a.w;
    r[4] = (__bf16)b.x; r[5] = (__bf16)b.y; r[6] = (__bf16)b.z; r[7] = (__bf16)b.w;
    return r;
}

// ---------------------------------------------------------------------------
// C = A(M x K, optional row-gather) @ W(N x K)^T [+bias]
// MODE 0: fp32 C row-major.  MODE 2: fp32 out[b][n][t], m = b*32+t (+bias).
// SWAP=1: blockIdx.x indexes M-tiles (fastest) so co-resident blocks share the
//         same W columns -> W read ~once from HBM (logits GEMM).
// One wave: one 16-row M tile x NT 16-col N tiles. block=256 (4 waves).
// ---------------------------------------------------------------------------
template <int NT, int MODE, int AF32, int WF32, int SWAP>
__global__ __launch_bounds__(256) void gemm_bt(
    const void* __restrict__ A, int lda, const int* __restrict__ aidx,
    const void* __restrict__ W, int K, const float* __restrict__ bias,
    void* __restrict__ Cout, int N)
{
    const int wave = threadIdx.x >> 6;
    const int lane = threadIdx.x & 63;
    const int quad = lane >> 4;
    const int mn   = lane & 15;

    const int mt  = SWAP ? blockIdx.x : blockIdx.y;
    const int ntb = SWAP ? blockIdx.y : blockIdx.x;
    const int nt0 = (ntb * 4 + wave) * NT;

    const int m = mt * 16 + mn;
    const long arow = aidx ? (long)aidx[m] : (long)m;
    const long aoff = arow * (long)lda + quad * 8;
    const long woff = (long)(nt0 * 16 + mn) * K + quad * 8;

    f32x4 acc[NT];
#pragma unroll
    for (int i = 0; i < NT; i++) acc[i] = (f32x4){0.f, 0.f, 0.f, 0.f};

    for (int k0 = 0; k0 < K; k0 += 32) {
        bf16x8 af;
        if (AF32) af = frag_from_f32((const float*)A + aoff + k0);
        else      af = *(const bf16x8*)((const __bf16*)A + aoff + k0);
#pragma unroll
        for (int i = 0; i < NT; i++) {
            bf16x8 wf;
            if (WF32) wf = frag_from_f32((const float*)W + woff + (long)i * 16 * K + k0);
            else      wf = *(const bf16x8*)((const __bf16*)W + woff + (long)i * 16 * K + k0);
            acc[i] = __builtin_amdgcn_mfma_f32_16x16x32_bf16(af, wf, acc[i], 0, 0, 0);
        }
    }

    const int row0 = mt * 16 + quad * 4;
#pragma unroll
    for (int i = 0; i < NT; i++) {
        const int n = (nt0 + i) * 16 + mn;
        const float bv = bias ? bias[n] : 0.0f;
#pragma unroll
        for (int r = 0; r < 4; r++) {
            const int mrow = row0 + r;
            const float v = acc[i][r] + bv;
            if (MODE == 0) {
                ((float*)Cout)[(long)mrow * N + n] = v;
            } else {
                const int b = mrow >> 5, t = mrow & 31;  // T_ = 32
                ((float*)Cout)[((long)b * N + n) * T_ + t] = v;
            }
        }
    }
}

// fp32 -> bf16 bulk convert (n multiple of 4).
__global__ __launch_bounds__(256) void cvt_kernel(
    const float* __restrict__ src, bf16* __restrict__ dst, int n)
{
    const int i = (blockIdx.x * 256 + threadIdx.x) * 4;
    if (i < n) {
        float4 v = *(const float4*)(src + i);
        dst[i + 0] = __float2bfloat16(v.x);
        dst[i + 1] = __float2bfloat16(v.y);
        dst[i + 2] = __float2bfloat16(v.z);
        dst[i + 3] = __float2bfloat16(v.w);
    }
}

// ---------------------------------------------------------------------------
// Fused LSTM step: zh = h_cur @ Whh^T (4 gate N-tiles strided by U per wave)
// with the gate pointwise math as the epilogue. Optionally (HASQ) extra blocks
// compute q = h_cur @ Wa^T + ba into qbuf. h is double-buffered: all reads from
// h_cur, the epilogue writes h_nxt -> no intra-kernel race with the q blocks.
// grid = (16 + 16*HASQ, B/16), block = 256 (4 waves).
// Each zh-wave: 16 u-columns x all 4 gates x 16 batch rows.
// ---------------------------------------------------------------------------
template <int HASQ>
__global__ __launch_bounds__(256) void lstm_step_kernel(
    const bf16* __restrict__ h_cur,
    const bf16* __restrict__ Whh,         // [4U][U] bf16
    const bf16* __restrict__ Wab,         // [U][U] bf16 (HASQ)
    const float* __restrict__ ba,         // [U]       (HASQ)
    float* __restrict__ qbuf,             // [B][U]    (HASQ)
    const float* __restrict__ zx_t, long zx_bs,   // zx + t-offset, batch stride
    const float* __restrict__ b_ih, const float* __restrict__ b_hh,
    float* __restrict__ c,
    bf16* __restrict__ h_nxt,
    bf16* __restrict__ obf, long obf_bs,  // encoder o slot (nullable)
    bf16* __restrict__ hc,  long hc_bs)   // decoder hc second half (nullable)
{
    const int wave = threadIdx.x >> 6, lane = threadIdx.x & 63;
    const int quad = lane >> 4, mn = lane & 15;
    const int b0 = blockIdx.y * 16;
    const long aoff = (long)(b0 + mn) * U_ + quad * 8;
    const __bf16* hp = (const __bf16*)h_cur;

    if (HASQ && blockIdx.x >= 16) {
        // ---- q = h_cur @ Wa^T + ba ----
        const int u0 = ((blockIdx.x - 16) * 4 + wave) * 16;
        const long woff = (long)(u0 + mn) * U_ + quad * 8;
        const __bf16* wp = (const __bf16*)Wab;
        f32x4 acc = (f32x4){0.f, 0.f, 0.f, 0.f};
#pragma unroll 4
        for (int k0 = 0; k0 < U_; k0 += 32) {
            bf16x8 af = *(const bf16x8*)(hp + aoff + k0);
            bf16x8 wf = *(const bf16x8*)(wp + woff + k0);
            acc = __builtin_amdgcn_mfma_f32_16x16x32_bf16(af, wf, acc, 0, 0, 0);
        }
        const int n = u0 + mn;
        const float bv = ba[n];
        const int r0 = b0 + quad * 4;
#pragma unroll
        for (int r = 0; r < 4; r++)
            qbuf[(long)(r0 + r) * U_ + n] = acc[r] + bv;
        return;
    }

    // ---- zh GEMM: 4 gates strided by U, then gate epilogue ----
    const int u0 = (blockIdx.x * 4 + wave) * 16;
    const __bf16* wp = (const __bf16*)Whh;
    long woff[4];
#pragma unroll
    for (int g = 0; g < 4; g++) woff[g] = (long)(g * U_ + u0 + mn) * U_ + quad * 8;

    f32x4 acc[4];
#pragma unroll
    for (int g = 0; g < 4; g++) acc[g] = (f32x4){0.f, 0.f, 0.f, 0.f};

#pragma unroll 4
    for (int k0 = 0; k0 < U_; k0 += 32) {
        bf16x8 af = *(const bf16x8*)(hp + aoff + k0);
#pragma unroll
        for (int g = 0; g < 4; g++) {
            bf16x8 wf = *(const bf16x8*)(wp + woff[g] + k0);
            acc[g] = __builtin_amdgcn_mfma_f32_16x16x32_bf16(af, wf, acc[g], 0, 0, 0);
        }
    }

    const int u = u0 + mn;
    float bsum[4];
#pragma unroll
    for (int g = 0; g < 4; g++) bsum[g] = b_ih[g * U_ + u] + b_hh[g * U_ + u];

    const int r0 = b0 + quad * 4;
#pragma unroll
    for (int r = 0; r < 4; r++) {
        const int b = r0 + r;
        const float* zxr = zx_t + (long)b * zx_bs;
        const float zi = acc[0][r] + zxr[u]          + bsum[0];
        const float zf = acc[1][r] + zxr[U_ + u]     + bsum[1];
        const float zg = acc[2][r] + zxr[2 * U_ + u] + bsum[2];
        const float zo = acc[3][r] + zxr[3 * U_ + u] + bsum[3];
        const long cu = (long)b * U_ + u;
        const float cv = sigf(zf) * c[cu] + sigf(zi) * tanhf(zg);
        const float hv = sigf(zo) * tanhf(cv);
        c[cu] = cv;
        const bf16 hb = __float2bfloat16(hv);
        h_nxt[cu] = hb;
        if (obf) obf[(long)b * obf_bs + u] = hb;
        if (hc)  hc[(long)b * hc_bs + u] = hb;
    }
}

// ---------------------------------------------------------------------------
// Attention step: scores = q . o[b,s,:]; softmax over s; ctx -> hc first half.
// grid = B_, block = 256. Vectorized loads (bf16x8 / float4 / bf16x4).
// ---------------------------------------------------------------------------
__global__ __launch_bounds__(256) void attn_kernel(
    const float* __restrict__ q, const bf16* __restrict__ o_enc,
    bf16* __restrict__ hc, long hc_bs)
{
    const int b = blockIdx.x;
    __shared__ float sw[S_];
    const int tid = threadIdx.x, wave = tid >> 6, lane = tid & 63;
    const float* qb = q + (long)b * U_;
    const bf16* ob = o_enc + (long)b * S_ * U_;

    // scores: wave handles s = wave*16 + j; lane covers 16 consecutive k.
    const float4 q0 = *(const float4*)(qb + lane * 16 + 0);
    const float4 q1 = *(const float4*)(qb + lane * 16 + 4);
    const float4 q2 = *(const float4*)(qb + lane * 16 + 8);
    const float4 q3 = *(const float4*)(qb + lane * 16 + 12);
    for (int j = 0; j < 16; j++) {
        const int s = wave * 16 + j;
        const __bf16* orow = (const __bf16*)(ob + (long)s * U_);
        bf16x8 v0 = *(const bf16x8*)(orow + lane * 16);
        bf16x8 v1 = *(const bf16x8*)(orow + lane * 16 + 8);
        float acc = q0.x * (float)v0[0] + q0.y * (float)v0[1]
                  + q0.z * (float)v0[2] + q0.w * (float)v0[3]
                  + q1.x * (float)v0[4] + q1.y * (float)v0[5]
                  + q1.z * (float)v0[6] + q1.w * (float)v0[7]
                  + q2.x * (float)v1[0] + q2.y * (float)v1[1]
                  + q2.z * (float)v1[2] + q2.w * (float)v1[3]
                  + q3.x * (float)v1[4] + q3.y * (float)v1[5]
                  + q3.z * (float)v1[6] + q3.w * (float)v1[7];
        for (int off = 32; off; off >>= 1) acc += __shfl_down(acc, off);
        if (lane == 0) sw[s] = acc;
    }
    __syncthreads();
    if (wave == 0) {
        float v = sw[lane];
        float mx = v;
        for (int off = 32; off; off >>= 1) mx = fmaxf(mx, __shfl_xor(mx, off));
        const float e = __expf(v - mx);
        float sum = e;
        for (int off = 32; off; off >>= 1) sum += __shfl_xor(sum, off);
        sw[lane] = e / sum;
    }
    __syncthreads();
    // ctx: each thread owns 4 consecutive u.
    const int u = tid * 4;
    float a0 = 0.f, a1 = 0.f, a2 = 0.f, a3 = 0.f;
    for (int s = 0; s < S_; s++) {
        const float w = sw[s];
        bf16x4 v = *(const bf16x4*)((const __bf16*)ob + (long)s * U_ + u);
        a0 += w * (float)v[0];
        a1 += w * (float)v[1];
        a2 += w * (float)v[2];
        a3 += w * (float)v[3];
    }
    bf16* out = hc + (long)b * hc_bs + u;
    out[0] = __float2bfloat16(a0);
    out[1] = __float2bfloat16(a1);
    out[2] = __float2bfloat16(a2);
    out[3] = __float2bfloat16(a3);
}

__global__ void build_idx(const int* __restrict__ y, int* __restrict__ idx)
{
    const int i = blockIdx.x * 256 + threadIdx.x;
    if (i < B_ * T_) {
        const int b = i >> 5, t = i & 31;
        idx[i] = y[b * (T_ + 1) + t];
    }
}

extern "C" void kernel_launch(void* const* d_in, const int* in_sizes, int n_in,
                              void* d_out, int out_size, void* d_ws, size_t ws_size,
                              hipStream_t stream)
{
    const int*   x       = (const int*)d_in[0];
    const int*   y       = (const int*)d_in[1];
    const float* enc_emb = (const float*)d_in[2];
    const float* dec_emb = (const float*)d_in[3];
    const float* W_ih_e  = (const float*)d_in[4];
    const float* W_hh_e  = (const float*)d_in[5];
    const float* b_ih_e  = (const float*)d_in[6];
    const float* b_hh_e  = (const float*)d_in[7];
    const float* Wa      = (const float*)d_in[8];
    const float* ba      = (const float*)d_in[9];
    const float* W_ih_d  = (const float*)d_in[10];
    const float* W_hh_d  = (const float*)d_in[11];
    const float* b_ih_d  = (const float*)d_in[12];
    const float* b_hh_d  = (const float*)d_in[13];
    const float* Wd      = (const float*)d_in[14];
    const float* bd      = (const float*)d_in[15];

    char* p = (char*)d_ws;
    auto alloc = [&](size_t bytes) { void* r = p; p += (bytes + 255) & ~255ull; return r; };
    float* zx_enc  = (float*)alloc((size_t)B_ * S_ * 4 * U_ * 4);   // 67 MB
    float* zx_dec  = (float*)alloc((size_t)B_ * T_ * 4 * U_ * 4);   // 34 MB
    bf16*  o_enc   = (bf16*)alloc((size_t)B_ * S_ * U_ * 2);        // 8.4 MB
    float* qbuf    = (float*)alloc((size_t)B_ * U_ * 4);
    float* cbuf    = (float*)alloc((size_t)B_ * U_ * 4);
    bf16*  hbf0    = (bf16*)alloc((size_t)B_ * U_ * 2);
    bf16*  hbf1    = (bf16*)alloc((size_t)B_ * U_ * 2);
    bf16*  hc_all  = (bf16*)alloc((size_t)B_ * T_ * 2 * U_ * 2);    // 8.4 MB
    bf16*  Whh_e_b = (bf16*)alloc((size_t)4 * U_ * U_ * 2);         // 8.4 MB
    bf16*  Whh_d_b = (bf16*)alloc((size_t)4 * U_ * U_ * 2);         // 8.4 MB
    bf16*  Wa_b    = (bf16*)alloc((size_t)U_ * U_ * 2);             // 2.1 MB
    int*   dec_idx = (int*)alloc((size_t)B_ * T_ * 4);
    bf16*  hb[2]   = {hbf0, hbf1};

    hipMemsetAsync(cbuf, 0, (size_t)B_ * U_ * 4, stream);
    hipMemsetAsync(hbf0, 0, (size_t)B_ * U_ * 2, stream);
    build_idx<<<8, 256, 0, stream>>>(y, dec_idx);

    // Multi-use weights -> bf16 once per launch.
    cvt_kernel<<<(4 * U_ * U_) / 1024, 256, 0, stream>>>(W_hh_e, Whh_e_b, 4 * U_ * U_);
    cvt_kernel<<<(4 * U_ * U_) / 1024, 256, 0, stream>>>(W_hh_d, Whh_d_b, 4 * U_ * U_);
    cvt_kernel<<<(U_ * U_) / 1024, 256, 0, stream>>>(Wa, Wa_b, U_ * U_);

    // Input projections (biases folded into step epilogue); fp32 A (gather) & W.
    gemm_bt<4, 0, 1, 1, 0><<<dim3((4 * U_) / 256, (B_ * S_) / 16), 256, 0, stream>>>(
        enc_emb, E_, x, W_ih_e, E_, nullptr, zx_enc, 4 * U_);
    gemm_bt<4, 0, 1, 1, 0><<<dim3((4 * U_) / 256, (B_ * T_) / 16), 256, 0, stream>>>(
        dec_emb, E_, dec_idx, W_ih_d, E_, nullptr, zx_dec, 4 * U_);

    // Encoder scan: one fused kernel per step.
    for (int t = 0; t < S_; t++) {
        lstm_step_kernel<0><<<dim3(16, B_ / 16), 256, 0, stream>>>(
            hb[t & 1], Whh_e_b, nullptr, nullptr, nullptr,
            zx_enc + (long)t * 4 * U_, (long)S_ * 4 * U_,
            b_ih_e, b_hh_e, cbuf, hb[1 - (t & 1)],
            o_enc + (long)t * U_, (long)S_ * U_, nullptr, 0);
    }
    // Encoder ran 64 steps: final h landed in hb[0] (t=63 writes hb[0]).

    // Decoder scan: fused {q-GEMM + zh-GEMM + gates} then attention.
    for (int t = 0; t < T_; t++) {
        lstm_step_kernel<1><<<dim3(32, B_ / 16), 256, 0, stream>>>(
            hb[t & 1], Whh_d_b, Wa_b, ba, qbuf,
            zx_dec + (long)t * 4 * U_, (long)T_ * 4 * U_,
            b_ih_d, b_hh_d, cbuf, hb[1 - (t & 1)],
            nullptr, 0, hc_all + (long)t * 2 * U_ + U_, (long)T_ * 2 * U_);
        attn_kernel<<<B_, 256, 0, stream>>>(
            qbuf, o_enc, hc_all + (long)t * 2 * U_, (long)T_ * 2 * U_);
    }

    // logits: hc_all (2048 x 2048 bf16) @ Wd^T (32000 x 2048 fp32) + bd
    // SWAP=1: M-tiles fastest so co-resident blocks share W columns.
    gemm_bt<4, 2, 0, 1, 1><<<dim3((B_ * T_) / 16, VD_ / 256), 256, 0, stream>>>(
        hc_all, 2 * U_, nullptr, Wd, 2 * U_, bd, d_out, VD_);
}

// Round 2
// 2767.898 us; speedup vs baseline: 3.5502x; 2.6555x over previous
//
#include <hip/hip_runtime.h>
#include <hip/hip_bf16.h>

// Seq2Seq: B=64 S=64 T=32 E=512 U=1024 VE=16000 VD=32000
// fp32 in/out; internal GEMMs bf16 MFMA.
// R2: attention deferred out of the decoder critical path (ctx only feeds the
//     logits); per-step kernel = 1 gate/wave + LDS exchange (256 blocks);
//     logits GEMM MT=4xNT=4 with bf16 Wd (ws-permitting) + XCD-chunk swizzle.

typedef __hip_bfloat16 bf16;
typedef __bf16 bf16x8 __attribute__((ext_vector_type(8)));
typedef __bf16 bf16x4 __attribute__((ext_vector_type(4)));
typedef float f32x4 __attribute__((ext_vector_type(4)));

#define B_ 64
#define S_ 64
#define T_ 32
#define E_ 512
#define U_ 1024
#define VD_ 32000

__device__ __forceinline__ float sigf(float x) { return 1.0f / (1.0f + __expf(-x)); }

__device__ __forceinline__ bf16x8 frag_from_f32(const float* __restrict__ p) {
    float4 a = *(const float4*)p;
    float4 b = *(const float4*)(p + 4);
    bf16x8 r;
    r[0] = (__bf16)a.x; r[1] = (__bf16)a.y; r[2] = (__bf16)a.z; r[3] = (__bf16)a.w;
    r[4] = (__bf16)b.x; r[5] = (__bf16)b.y; r[6] = (__bf16)b.z; r[7] = (__bf16)b.w;
    return r;
}

// ---------------------------------------------------------------------------
// Generic C = A(M x K, optional row-gather) @ W(N x K)^T [+bias], fp32 C.
// One wave: one 16-row M tile x NT 16-col N tiles. block=256 (4 waves).
// grid = (N/(64*NT), M/16). Used for input projections and the Q projection.
// ---------------------------------------------------------------------------
template <int NT, int AF32, int WF32>
__global__ __launch_bounds__(256) void gemm_bt(
    const void* __restrict__ A, int lda, const int* __restrict__ aidx,
    const void* __restrict__ W, int K, const float* __restrict__ bias,
    float* __restrict__ Cout, int N)
{
    const int wave = threadIdx.x >> 6;
    const int lane = threadIdx.x & 63;
    const int quad = lane >> 4;
    const int mn   = lane & 15;

    const int mt  = blockIdx.y;
    const int nt0 = (blockIdx.x * 4 + wave) * NT;

    const int m = mt * 16 + mn;
    const long arow = aidx ? (long)aidx[m] : (long)m;
    const long aoff = arow * (long)lda + quad * 8;
    const long woff = (long)(nt0 * 16 + mn) * K + quad * 8;

    f32x4 acc[NT];
#pragma unroll
    for (int i = 0; i < NT; i++) acc[i] = (f32x4){0.f, 0.f, 0.f, 0.f};

    for (int k0 = 0; k0 < K; k0 += 32) {
        bf16x8 af;
        if (AF32) af = frag_from_f32((const float*)A + aoff + k0);
        else      af = *(const bf16x8*)((const __bf16*)A + aoff + k0);
#pragma unroll
        for (int i = 0; i < NT; i++) {
            bf16x8 wf;
            if (WF32) wf = frag_from_f32((const float*)W + woff + (long)i * 16 * K + k0);
            else      wf = *(const bf16x8*)((const __bf16*)W + woff + (long)i * 16 * K + k0);
            acc[i] = __builtin_amdgcn_mfma_f32_16x16x32_bf16(af, wf, acc[i], 0, 0, 0);
        }
    }

    const int row0 = mt * 16 + quad * 4;
#pragma unroll
    for (int i = 0; i < NT; i++) {
        const int n = (nt0 + i) * 16 + mn;
        const float bv = bias ? bias[n] : 0.0f;
#pragma unroll
        for (int r = 0; r < 4; r++)
            Cout[(long)(row0 + r) * N + n] = acc[i][r] + bv;
    }
}

// ---------------------------------------------------------------------------
// Logits GEMM: out[b][n][t] = hc_all(2048 x 2048 bf16) @ Wd(32000 x 2048)^T + bd
// Per wave: MT=4 M-subtiles x NT=4 N-subtiles (64x64). Block: 4 waves over N
// (64 M x 256 N). grid (32, 125), XCD-chunked swizzle so each XCD owns a
// contiguous nid range -> per-y W chunk stays in its L2; W read ~once from HBM.
// ---------------------------------------------------------------------------
template <int WF32>
__global__ __launch_bounds__(256) void logits_kernel(
    const bf16* __restrict__ A,        // hc_all, lda = 2U
    const void* __restrict__ W,        // [VD][2U] bf16 or fp32
    const float* __restrict__ bias,
    float* __restrict__ out)
{
    const int K = 2 * U_;
    const int wave = threadIdx.x >> 6, lane = threadIdx.x & 63;
    const int quad = lane >> 4, mn = lane & 15;

    const int bid = blockIdx.y * gridDim.x + blockIdx.x;   // 0..3999, x fastest
    const int nid = (bid & 7) * 500 + (bid >> 3);          // 4000 = 8 * 500
    const int mtb = nid & 31;                              // 32 M-blocks (64 rows)
    const int ntb = nid >> 5;                              // 125 N-blocks (256 cols)

    const int m0 = mtb * 64;
    const int n0 = ntb * 256 + wave * 64;

    long aoff[4], woff[4];
#pragma unroll
    for (int m = 0; m < 4; m++) aoff[m] = (long)(m0 + m * 16 + mn) * K + quad * 8;
#pragma unroll
    for (int i = 0; i < 4; i++) woff[i] = (long)(n0 + i * 16 + mn) * K + quad * 8;

    f32x4 acc[4][4];
#pragma unroll
    for (int m = 0; m < 4; m++)
#pragma unroll
        for (int i = 0; i < 4; i++) acc[m][i] = (f32x4){0.f, 0.f, 0.f, 0.f};

#pragma unroll 2
    for (int k0 = 0; k0 < K; k0 += 32) {
        bf16x8 a[4];
#pragma unroll
        for (int m = 0; m < 4; m++)
            a[m] = *(const bf16x8*)((const __bf16*)A + aoff[m] + k0);
#pragma unroll
        for (int i = 0; i < 4; i++) {
            bf16x8 wf;
            if (WF32) wf = frag_from_f32((const float*)W + woff[i] + k0);
            else      wf = *(const bf16x8*)((const __bf16*)W + woff[i] + k0);
#pragma unroll
            for (int m = 0; m < 4; m++)
                acc[m][i] = __builtin_amdgcn_mfma_f32_16x16x32_bf16(a[m], wf, acc[m][i], 0, 0, 0);
        }
    }

#pragma unroll
    for (int i = 0; i < 4; i++) {
        const int n = n0 + i * 16 + mn;
        const float bv = bias[n];
#pragma unroll
        for (int m = 0; m < 4; m++) {
            const int row0 = m0 + m * 16 + quad * 4;
#pragma unroll
            for (int r = 0; r < 4; r++) {
                const int mrow = row0 + r;
                const int b = mrow >> 5, t = mrow & 31;   // T_ = 32
                out[((long)b * VD_ + n) * T_ + t] = acc[m][i][r] + bv;
            }
        }
    }
}

// fp32 -> bf16 bulk convert (n multiple of 4).
__global__ __launch_bounds__(256) void cvt_kernel(
    const float* __restrict__ src, bf16* __restrict__ dst, int n)
{
    const int i = (blockIdx.x * 256 + threadIdx.x) * 4;
    if (i < n) {
        float4 v = *(const float4*)(src + i);
        dst[i + 0] = __float2bfloat16(v.x);
        dst[i + 1] = __float2bfloat16(v.y);
        dst[i + 2] = __float2bfloat16(v.z);
        dst[i + 3] = __float2bfloat16(v.w);
    }
}

// ---------------------------------------------------------------------------
// Fused LSTM step, 1 gate per wave + LDS exchange.
// grid = (U/16 = 64, B/16 = 4) = 256 blocks, block = 256 (4 waves).
// Wave g computes z_g (16 batch x 16 u) via MFMA; waves exchange via LDS;
// epilogue: 1 thread per (b,u) does the gate math, updates c, stores h bf16.
// h is stored directly into its o_enc / hc_all slot (slot t-1 read, t written).
// ---------------------------------------------------------------------------
__global__ __launch_bounds__(256) void lstm_step_kernel(
    const bf16* __restrict__ h_cur, long h_lda,
    const bf16* __restrict__ Whh,                     // [4U][U] bf16
    const float* __restrict__ zx_t, long zx_bs,       // zx + t-offset, batch stride
    const float* __restrict__ b_ih, const float* __restrict__ b_hh,
    float* __restrict__ c,
    bf16* __restrict__ h_out, long h_lda_out)
{
    __shared__ float zbuf[4][16][17];
    const int tid = threadIdx.x;
    const int g = tid >> 6, lane = tid & 63;
    const int quad = lane >> 4, mn = lane & 15;
    const int u0 = blockIdx.x * 16, b0 = blockIdx.y * 16;

    const __bf16* hp = (const __bf16*)h_cur;
    const __bf16* wp = (const __bf16*)Whh;
    const long aoff = (long)(b0 + mn) * h_lda + quad * 8;
    const long woff = (long)(g * U_ + u0 + mn) * (long)U_ + quad * 8;

    f32x4 acc = (f32x4){0.f, 0.f, 0.f, 0.f};
#pragma unroll 8
    for (int k0 = 0; k0 < U_; k0 += 32) {
        bf16x8 af = *(const bf16x8*)(hp + aoff + k0);
        bf16x8 wf = *(const bf16x8*)(wp + woff + k0);
        acc = __builtin_amdgcn_mfma_f32_16x16x32_bf16(af, wf, acc, 0, 0, 0);
    }
#pragma unroll
    for (int r = 0; r < 4; r++) zbuf[g][quad * 4 + r][mn] = acc[r];
    __syncthreads();

    const int bl = tid >> 4, uc = tid & 15;
    const int b = b0 + bl, u = u0 + uc;
    const float* zxr = zx_t + (long)b * zx_bs;
    const float zi = zbuf[0][bl][uc] + zxr[u]           + b_ih[u]           + b_hh[u];
    const float zf = zbuf[1][bl][uc] + zxr[U_ + u]      + b_ih[U_ + u]      + b_hh[U_ + u];
    const float zg = zbuf[2][bl][uc] + zxr[2 * U_ + u]  + b_ih[2 * U_ + u]  + b_hh[2 * U_ + u];
    const float zo = zbuf[3][bl][uc] + zxr[3 * U_ + u]  + b_ih[3 * U_ + u]  + b_hh[3 * U_ + u];
    const long cu = (long)b * U_ + u;
    const float cv = sigf(zf) * c[cu] + sigf(zi) * tanhf(zg);
    const float hv = sigf(zo) * tanhf(cv);
    c[cu] = cv;
    h_out[(long)b * h_lda_out + u] = __float2bfloat16(hv);
}

// ---------------------------------------------------------------------------
// Batched attention for ALL decoder steps (off critical path).
// grid = B*T = 2048 blocks, block = 256. Per block (b,t): scores over 64 s,
// softmax, ctx(1024) -> hc_all[b][t][0..U).
// ---------------------------------------------------------------------------
__global__ __launch_bounds__(256) void attn_all_kernel(
    const float* __restrict__ q,       // [B*T][U]
    const bf16* __restrict__ o_enc,    // [B][S][U]
    bf16* __restrict__ hc_all)         // [B][T][2U]
{
    const int bt = blockIdx.x;
    const int b = bt >> 5;             // T_ = 32
    __shared__ float sw[S_];
    const int tid = threadIdx.x, wave = tid >> 6, lane = tid & 63;
    const float* qb = q + (long)bt * U_;
    const bf16* ob = o_enc + (long)b * S_ * U_;

    const float4 q0 = *(const float4*)(qb + lane * 16 + 0);
    const float4 q1 = *(const float4*)(qb + lane * 16 + 4);
    const float4 q2 = *(const float4*)(qb + lane * 16 + 8);
    const float4 q3 = *(const float4*)(qb + lane * 16 + 12);
    for (int j = 0; j < 16; j++) {
        const int s = wave * 16 + j;
        const __bf16* orow = (const __bf16*)(ob + (long)s * U_);
        bf16x8 v0 = *(const bf16x8*)(orow + lane * 16);
        bf16x8 v1 = *(const bf16x8*)(orow + lane * 16 + 8);
        float acc = q0.x * (float)v0[0] + q0.y * (float)v0[1]
                  + q0.z * (float)v0[2] + q0.w * (float)v0[3]
                  + q1.x * (float)v0[4] + q1.y * (float)v0[5]
                  + q1.z * (float)v0[6] + q1.w * (float)v0[7]
                  + q2.x * (float)v1[0] + q2.y * (float)v1[1]
                  + q2.z * (float)v1[2] + q2.w * (float)v1[3]
                  + q3.x * (float)v1[4] + q3.y * (float)v1[5]
                  + q3.z * (float)v1[6] + q3.w * (float)v1[7];
        for (int off = 32; off; off >>= 1) acc += __shfl_down(acc, off);
        if (lane == 0) sw[s] = acc;
    }
    __syncthreads();
    if (wave == 0) {
        float v = sw[lane];
        float mx = v;
        for (int off = 32; off; off >>= 1) mx = fmaxf(mx, __shfl_xor(mx, off));
        const float e = __expf(v - mx);
        float sum = e;
        for (int off = 32; off; off >>= 1) sum += __shfl_xor(sum, off);
        sw[lane] = e / sum;
    }
    __syncthreads();
    const int u = tid * 4;
    float a0 = 0.f, a1 = 0.f, a2 = 0.f, a3 = 0.f;
    for (int s = 0; s < S_; s++) {
        const float w = sw[s];
        bf16x4 v = *(const bf16x4*)((const __bf16*)ob + (long)s * U_ + u);
        a0 += w * (float)v[0];
        a1 += w * (float)v[1];
        a2 += w * (float)v[2];
        a3 += w * (float)v[3];
    }
    bf16* outp = hc_all + (long)bt * 2 * U_ + u;
    outp[0] = __float2bfloat16(a0);
    outp[1] = __float2bfloat16(a1);
    outp[2] = __float2bfloat16(a2);
    outp[3] = __float2bfloat16(a3);
}

__global__ void build_idx(const int* __restrict__ y, int* __restrict__ idx)
{
    const int i = blockIdx.x * 256 + threadIdx.x;
    if (i < B_ * T_) {
        const int b = i >> 5, t = i & 31;
        idx[i] = y[b * (T_ + 1) + t];
    }
}

extern "C" void kernel_launch(void* const* d_in, const int* in_sizes, int n_in,
                              void* d_out, int out_size, void* d_ws, size_t ws_size,
                              hipStream_t stream)
{
    const int*   x       = (const int*)d_in[0];
    const int*   y       = (const int*)d_in[1];
    const float* enc_emb = (const float*)d_in[2];
    const float* dec_emb = (const float*)d_in[3];
    const float* W_ih_e  = (const float*)d_in[4];
    const float* W_hh_e  = (const float*)d_in[5];
    const float* b_ih_e  = (const float*)d_in[6];
    const float* b_hh_e  = (const float*)d_in[7];
    const float* Wa      = (const float*)d_in[8];
    const float* ba      = (const float*)d_in[9];
    const float* W_ih_d  = (const float*)d_in[10];
    const float* W_hh_d  = (const float*)d_in[11];
    const float* b_ih_d  = (const float*)d_in[12];
    const float* b_hh_d  = (const float*)d_in[13];
    const float* Wd      = (const float*)d_in[14];
    const float* bd      = (const float*)d_in[15];

    char* p = (char*)d_ws;
    auto alloc = [&](size_t bytes) { void* r = p; p += (bytes + 255) & ~255ull; return r; };
    float* zx_enc  = (float*)alloc((size_t)B_ * S_ * 4 * U_ * 4);   // 67 MB
    float* zx_dec  = (float*)alloc((size_t)B_ * T_ * 4 * U_ * 4);   // 34 MB
    bf16*  o_enc   = (bf16*)alloc((size_t)B_ * S_ * U_ * 2);        // 8.4 MB
    float* qbuf    = (float*)alloc((size_t)B_ * T_ * U_ * 4);       // 8.4 MB
    float* cbuf    = (float*)alloc((size_t)B_ * U_ * 4);
    bf16*  h0      = (bf16*)alloc((size_t)B_ * U_ * 2);
    bf16*  hc_all  = (bf16*)alloc((size_t)B_ * T_ * 2 * U_ * 2);    // 8.4 MB
    bf16*  Whh_e_b = (bf16*)alloc((size_t)4 * U_ * U_ * 2);         // 8.4 MB
    bf16*  Whh_d_b = (bf16*)alloc((size_t)4 * U_ * U_ * 2);         // 8.4 MB
    bf16*  Wa_b    = (bf16*)alloc((size_t)U_ * U_ * 2);             // 2.1 MB
    bf16*  Wih_e_b = (bf16*)alloc((size_t)4 * U_ * E_ * 2);         // 4.2 MB
    bf16*  Wih_d_b = (bf16*)alloc((size_t)4 * U_ * E_ * 2);         // 4.2 MB
    int*   dec_idx = (int*)alloc((size_t)B_ * T_ * 4);

    // Wd bf16 copy (131 MB) only if workspace allows; else fp32 fallback.
    const size_t wd_bytes = (size_t)VD_ * 2 * U_ * 2;
    bf16* Wd_b = nullptr;
    if (ws_size >= (size_t)(p - (char*)d_ws) + wd_bytes + 256)
        Wd_b = (bf16*)alloc(wd_bytes);

    hipMemsetAsync(cbuf, 0, (size_t)B_ * U_ * 4, stream);
    hipMemsetAsync(h0, 0, (size_t)B_ * U_ * 2, stream);
    build_idx<<<8, 256, 0, stream>>>(y, dec_idx);

    // Weights -> bf16 once per launch.
    cvt_kernel<<<(4 * U_ * U_) / 1024, 256, 0, stream>>>(W_hh_e, Whh_e_b, 4 * U_ * U_);
    cvt_kernel<<<(4 * U_ * U_) / 1024, 256, 0, stream>>>(W_hh_d, Whh_d_b, 4 * U_ * U_);
    cvt_kernel<<<(U_ * U_) / 1024, 256, 0, stream>>>(Wa, Wa_b, U_ * U_);
    cvt_kernel<<<(4 * U_ * E_) / 1024, 256, 0, stream>>>(W_ih_e, Wih_e_b, 4 * U_ * E_);
    cvt_kernel<<<(4 * U_ * E_) / 1024, 256, 0, stream>>>(W_ih_d, Wih_d_b, 4 * U_ * E_);
    if (Wd_b)
        cvt_kernel<<<(VD_ * 2 * U_) / 1024, 256, 0, stream>>>(Wd, Wd_b, VD_ * 2 * U_);

    // Input projections (biases folded into step epilogue). A: fp32 gather.
    gemm_bt<4, 1, 0><<<dim3((4 * U_) / 256, (B_ * S_) / 16), 256, 0, stream>>>(
        enc_emb, E_, x, Wih_e_b, E_, nullptr, zx_enc, 4 * U_);
    gemm_bt<4, 1, 0><<<dim3((4 * U_) / 256, (B_ * T_) / 16), 256, 0, stream>>>(
        dec_emb, E_, dec_idx, Wih_d_b, E_, nullptr, zx_dec, 4 * U_);

    // Encoder scan: h lives in o_enc slots (slot t-1 read, slot t written).
    for (int t = 0; t < S_; t++) {
        const bf16* hc_ = (t == 0) ? h0 : o_enc + (long)(t - 1) * U_;
        const long  hl_ = (t == 0) ? (long)U_ : (long)S_ * U_;
        lstm_step_kernel<<<dim3(U_ / 16, B_ / 16), 256, 0, stream>>>(
            hc_, hl_, Whh_e_b,
            zx_enc + (long)t * 4 * U_, (long)S_ * 4 * U_,
            b_ih_e, b_hh_e, cbuf,
            o_enc + (long)t * U_, (long)S_ * U_);
    }

    // Decoder scan (pure LSTM; attention deferred). h lives in hc_all 2nd half.
    for (int t = 0; t < T_; t++) {
        const bf16* hc_ = (t == 0) ? o_enc + (long)(S_ - 1) * U_
                                   : hc_all + (long)(t - 1) * 2 * U_ + U_;
        const long  hl_ = (t == 0) ? (long)S_ * U_ : (long)T_ * 2 * U_;
        lstm_step_kernel<<<dim3(U_ / 16, B_ / 16), 256, 0, stream>>>(
            hc_, hl_, Whh_d_b,
            zx_dec + (long)t * 4 * U_, (long)T_ * 4 * U_,
            b_ih_d, b_hh_d, cbuf,
            hc_all + (long)t * 2 * U_ + U_, (long)T_ * 2 * U_);
    }

    // Q for all decoder steps: (B*T x U) = H_dec @ Wa^T + ba.
    gemm_bt<4, 0, 0><<<dim3(U_ / 256, (B_ * T_) / 16), 256, 0, stream>>>(
        hc_all + U_, 2 * U_, nullptr, Wa_b, U_, ba, qbuf, U_);

    // Batched attention: ctx for all (b,t) -> hc_all first half.
    attn_all_kernel<<<B_ * T_, 256, 0, stream>>>(qbuf, o_enc, hc_all);

    // Logits.
    if (Wd_b)
        logits_kernel<0><<<dim3(32, 125), 256, 0, stream>>>(hc_all, Wd_b, bd, (float*)d_out);
    else
        logits_kernel<1><<<dim3(32, 125), 256, 0, stream>>>(hc_all, Wd, bd, (float*)d_out);
}